// Round 18
// baseline (58.447 us; speedup 1.0000x reference)
//
#include <hip/hip_runtime.h>
#include <hip/hip_bf16.h>
#include <math.h>

#define BB 2
#define CCH 64
#define HH 128
#define WWD 128
#define HWv (HH*WWD)
#define KK 9
#define KSTEP 18        // 576/32
#define OMKS 36         // 1152/32
// 2-row x 32-col tiles
#define TCOLS 34
#define CSTR 72         // padded 64-ch run stride (bf16): 64 + 8
#define CSTR2 136       // padded 128-ch run stride (bf16): 128 + 8
#define DROW 584        // deform samp row stride (bf16): 576 + 8

typedef __attribute__((ext_vector_type(8))) short bf16x8;
typedef __attribute__((ext_vector_type(4))) float f32x4;
typedef unsigned short u16;
typedef unsigned int u32;

__device__ inline u16 f2bf(float f) {
  __hip_bfloat16 h = __float2bfloat16(f);
  return *reinterpret_cast<u16*>(&h);
}
__device__ inline u32 f2bf2(float lo, float hi) {
  return ((u32)f2bf(hi) << 16) | (u32)f2bf(lo);
}
__device__ inline float bfLO(u32 v) { return __uint_as_float(v << 16); }
__device__ inline float bfHI(u32 v) { return __uint_as_float(v & 0xffff0000u); }
__device__ inline float bf2f(u16 v) { return __uint_as_float((u32)v << 16); }

// ==== kernel 1: blocks [0,512) = y-transpose + conv1x1 (w0 packed in-reg);
//                blocks [512,1088) = weight packs for dc/w1/w2/om ===========
__global__ __launch_bounds__(256) void c1y_pack_k(const float* __restrict__ x,
    const float* __restrict__ y, const float* __restrict__ w0,
    const float* __restrict__ b0, const float* __restrict__ w_dc,
    const float* __restrict__ w1, const float* __restrict__ w2,
    const float* __restrict__ w_om, u16* __restrict__ x0bf,
    u16* __restrict__ yt, u16* __restrict__ pk_dc, u16* __restrict__ pk_w1,
    u16* __restrict__ pk_w2, u16* __restrict__ pk_om) {
  #define S1ROW 72
  __shared__ __align__(16) float smem[64 * 65];    // 16,640 B; aliased below
  int tid = threadIdx.x;

  if (blockIdx.x >= 512) {                         // ---- pack path ----
    int blk = blockIdx.x - 512;                    // 0..575
    if (blk < 432) {
      const float* w = blk < 144 ? w_dc : (blk < 288 ? w1 : w2);
      u16* dst = blk < 144 ? pk_dc : (blk < 288 ? pk_w1 : pk_w2);
      int idx = (blk % 144) * 256 + tid;
      int j = idx & 7, l = (idx >> 3) & 63;
      int s = (idx >> 9) % 18, q = idx / 9216;
      int co = q * 16 + (l & 15);
      int kp = s * 32 + (l >> 4) * 8 + j;          // < 576
      dst[idx] = f2bf(w[(co * 64 + (kp & 63)) * 9 + (kp >> 6)]);
    } else {
      int idx = (blk - 432) * 256 + tid;
      int j = idx & 7, l = (idx >> 3) & 63;
      int s = (idx >> 9) % 36, q = idx / 18432;
      int co = q * 16 + (l & 15);
      int kp = s * 32 + (l >> 4) * 8 + j;          // < 1152
      pk_om[idx] = (co < 27)
          ? f2bf(w_om[(co * 128 + (kp & 127)) * 9 + (kp >> 7)]) : (u16)0;
    }
    return;
  }

  // ---- conv1x1y path (XCD-swizzled) ----
  u16* samp1 = (u16*)smem;                         // needs 9,216 B
  int lane = tid & 63, q = tid >> 6;
  int cblk = (blockIdx.x & 7) * 64 + (blockIdx.x >> 3);
  int pixbase = cblk * 64;
  int hwb = pixbase & (HWv - 1);
  int b = pixbase >> 14;
  int co = q * 16 + (lane & 15);
  int g = lane >> 4;

  // w0 fragments in-register (L2-resident 16 KB table)
  bf16x8 wfrag[2];
  #pragma unroll
  for (int s = 0; s < 2; s++) {
    const float* wp = w0 + co * 64 + s * 32 + g * 8;
    u16 tw[8];
    #pragma unroll
    for (int j = 0; j < 8; j++) tw[j] = f2bf(wp[j]);
    wfrag[s] = *(bf16x8*)tw;
  }

  // ---- phase Y: transpose y for these 64 px ----
  {
    const float* src = y + (size_t)b * CCH * HWv;
    #pragma unroll
    for (int i = 0; i < 16; i++) {
      int ci = i * 4 + q;
      smem[ci * 65 + lane] = src[(size_t)ci * HWv + hwb + lane];
    }
    __syncthreads();
    u32* dst32 = (u32*)(yt + ((size_t)b * HWv + hwb) * 64);
    int lane2 = tid & 31, rr = tid >> 5;
    #pragma unroll
    for (int i = 0; i < 8; i++) {
      int row = i * 8 + rr;
      dst32[row * 32 + lane2] = f2bf2(smem[(2 * lane2) * 65 + row],
                                      smem[(2 * lane2 + 1) * 65 + row]);
    }
    __syncthreads();                               // smem dead -> reuse
  }

  // ---- phase X: conv1x1 ----
  {
    u16 tmp[16];
    #pragma unroll
    for (int i = 0; i < 16; i++) {
      int ci = q * 16 + i;
      tmp[i] = f2bf(x[((size_t)b * CCH + ci) * HWv + hwb + lane]);
    }
    #pragma unroll
    for (int i = 0; i < 2; i++)
      *(bf16x8*)(samp1 + lane * S1ROW + q * 16 + i * 8) = *(bf16x8*)(tmp + i * 8);
  }
  __syncthreads();
  f32x4 acc[4] = {{0,0,0,0},{0,0,0,0},{0,0,0,0},{0,0,0,0}};
  #pragma unroll
  for (int s = 0; s < 2; s++) {
    #pragma unroll
    for (int t = 0; t < 4; t++) {
      bf16x8 a = *(const bf16x8*)(samp1 + (t * 16 + (lane & 15)) * S1ROW + g * 8 + s * 32);
      acc[t] = __builtin_amdgcn_mfma_f32_16x16x32_bf16(a, wfrag[s], acc[t], 0, 0, 0);
    }
  }
  float bv = b0[co];
  u16* dst = x0bf + ((size_t)b * HWv + hwb + g * 4) * 64 + co;
  #pragma unroll
  for (int t = 0; t < 4; t++)
    #pragma unroll
    for (int r = 0; r < 4; r++)
      dst[(size_t)(t * 16 + r) * 64] = f2bf(acc[t][r] + bv);
}

// ==== FUSED om conv + deform conv, 2-row x 32-col tile, 512 thr ============
// XCD-swizzled blocks; single prm pass; uint4 stage, uint2 gather.
__global__ __launch_bounds__(512) void omd_k(const u16* __restrict__ x0bf,
    const u16* __restrict__ yt, const u16* __restrict__ pk_om,
    const u16* __restrict__ pk_dc, const float* __restrict__ b_om,
    const float* __restrict__ b_dc, u16* __restrict__ ob) {
  __shared__ __align__(16) u16 A[18688];           // 37,376 B (stage / dsamp)
  __shared__ __align__(16) int prm[576][8];        // 18,432 B (both rows)
  __shared__ __align__(16) float omv[64 * 28];     //  7,168 B   (tot 62,976)
  u32* A32 = (u32*)A;
  u32* dsamp32 = (u32*)A;
  u16* dsamp = A;
  int tid = threadIdx.x;
  int lane = tid & 63, q = tid >> 6;
  int blk = (blockIdx.x & 7) * 64 + (blockIdx.x >> 3);   // XCD swizzle (512)
  int wq = blk & 3, rp = (blk >> 2) & 63, b = blk >> 8;
  int h0 = rp * 2, wb = wq * 32;
  const u32* x0b32 = (const u32*)x0bf + (size_t)b * HWv * 32;
  const u32* yt32  = (const u32*)yt + (size_t)b * HWv * 32;

  // ---- phase 1: stage [4][34][128ch]; 32 groups of 16 lanes, uint4
  {
    int lane2 = tid & 15, g16 = tid >> 4;
    const u32* srcb = (lane2 < 8) ? (x0b32 + lane2 * 4)
                                  : (yt32 + (lane2 - 8) * 4);
    #pragma unroll
    for (int i = 0; i < 5; i++) {
      int u = g16 + 32 * i;
      if (u < 4 * TCOLS) {
        int r = u / TCOLS, c = u % TCOLS;
        int hh = h0 - 1 + r, ww = wb - 1 + c;
        uint4 v = {0u, 0u, 0u, 0u};
        if ((unsigned)hh < HH && (unsigned)ww < WWD)
          v = *(const uint4*)(srcb + (size_t)(hh * WWD + ww) * 32);
        *(uint4*)(A32 + u * (CSTR2 / 2) + lane2 * 4) = v;
      }
    }
  }
  __syncthreads();

  // ---- phase 2: om MFMA
  {
    int r = q & 1, cg = (q >> 1) & 1, cohalf = q >> 2;
    f32x4 acc = {0.f, 0.f, 0.f, 0.f};
    const bf16x8* bp = (const bf16x8*)pk_om + (size_t)(cohalf * OMKS) * 64 + lane;
    #pragma unroll
    for (int s = 0; s < OMKS; s++) {
      int kk = s >> 2;
      int addr = ((r + kk / 3) * TCOLS + cg * 16 + (lane & 15) + (kk % 3)) * CSTR2
                 + (s & 3) * 32 + (lane >> 4) * 8;
      bf16x8 a = *(const bf16x8*)(A + addr);
      acc = __builtin_amdgcn_mfma_f32_16x16x32_bf16(a, bp[(size_t)s * 64], acc, 0, 0, 0);
    }
    int co = cohalf * 16 + (lane & 15);
    if (co < 27) {
      float bv = b_om[co];
      int px = r * 32 + cg * 16 + (lane >> 4) * 4;
      #pragma unroll
      for (int j = 0; j < 4; j++)
        omv[(px + j) * 28 + co] = acc[j] + bv;
    }
  }
  __syncthreads();

  // ---- phase 3a: prm for BOTH rows (576 entries over 512 threads)
  #pragma unroll
  for (int t = 0; t < 2; t++) {
    int u = tid + 512 * t;
    if (u < 576) {
      int pl = u / KK, k = u % KK;                 // pl 0..63
      int r2 = pl >> 5, cl = pl & 31;
      const float* omp = omv + pl * 28;
      float dy = omp[2 * k], dx = omp[2 * k + 1];
      float mk = 2.f / (1.f + expf(-omp[18 + k]));
      float ys = (float)(h0 + r2 - 1 + k / 3) + dy;
      float xs = (float)(wb + cl - 1 + k % 3) + dx;
      float y0f = floorf(ys), x0f = floorf(xs);
      float ty = ys - y0f, tx = xs - x0f;
      int yi = (int)y0f, xi = (int)x0f;
      bool y0v = (unsigned)yi < HH, y1v = (unsigned)(yi + 1) < HH;
      bool x0v = (unsigned)xi < WWD, x1v = (unsigned)(xi + 1) < WWD;
      float w00 = (1.f - ty) * (1.f - tx) * mk * ((y0v && x0v) ? 1.f : 0.f);
      float w01 = (1.f - ty) * tx * mk * ((y0v && x1v) ? 1.f : 0.f);
      float w10 = ty * (1.f - tx) * mk * ((y1v && x0v) ? 1.f : 0.f);
      float w11 = ty * tx * mk * ((y1v && x1v) ? 1.f : 0.f);
      int* p = prm[u];
      // offsets in u32 units of NHWC bf16: row = 128*32, col = 32
      *(int4*)p = make_int4(min(max(yi, 0), HH - 1) * (WWD * 32),
                            min(max(yi + 1, 0), HH - 1) * (WWD * 32),
                            min(max(xi, 0), WWD - 1) * 32,
                            min(max(xi + 1, 0), WWD - 1) * 32);
      *(int4*)(p + 4) = make_int4(__float_as_int(w00), __float_as_int(w01),
                                  __float_as_int(w10), __float_as_int(w11));
    }
  }
  __syncthreads();

  // ---- phase 3b/3c: per row: gather (16-lane uint2 groups) -> MFMA -> ob
  #pragma unroll
  for (int h2 = 0; h2 < 2; h2++) {
    {
      int lane4 = tid & 15, g16 = tid >> 4;        // 32 groups
      const u32* ytb = yt32 + lane4 * 2;
      #pragma unroll
      for (int i = 0; i < 9; i++) {
        int u = g16 + 32 * i;                      // 0..287
        int k = u % 9, pix = u / 9;
        const int* pp = prm[h2 * 288 + u];
        int4 pa = *(const int4*)pp;
        int4 pb = *(const int4*)(pp + 4);
        uint2 v00 = *(const uint2*)(ytb + pa.x + pa.z);
        uint2 v01 = *(const uint2*)(ytb + pa.x + pa.w);
        uint2 v10 = *(const uint2*)(ytb + pa.y + pa.z);
        uint2 v11 = *(const uint2*)(ytb + pa.y + pa.w);
        float w00 = __int_as_float(pb.x), w01 = __int_as_float(pb.y);
        float w10 = __int_as_float(pb.z), w11 = __int_as_float(pb.w);
        float a0 = fmaf(bfLO(v00.x), w00, fmaf(bfLO(v01.x), w01,
                   fmaf(bfLO(v10.x), w10, bfLO(v11.x) * w11)));
        float a1 = fmaf(bfHI(v00.x), w00, fmaf(bfHI(v01.x), w01,
                   fmaf(bfHI(v10.x), w10, bfHI(v11.x) * w11)));
        float a2 = fmaf(bfLO(v00.y), w00, fmaf(bfLO(v01.y), w01,
                   fmaf(bfLO(v10.y), w10, bfLO(v11.y) * w11)));
        float a3 = fmaf(bfHI(v00.y), w00, fmaf(bfHI(v01.y), w01,
                   fmaf(bfHI(v10.y), w10, bfHI(v11.y) * w11)));
        uint2 o = {f2bf2(a0, a1), f2bf2(a2, a3)};
        *(uint2*)(dsamp32 + pix * (DROW / 2) + k * 32 + lane4 * 2) = o;
      }
    }
    __syncthreads();
    {
      int qq = q & 3, pxg = q >> 2;
      f32x4 acc = {0.f, 0.f, 0.f, 0.f};
      const u16* arow = dsamp + (pxg * 16 + (lane & 15)) * DROW + (lane >> 4) * 8;
      const bf16x8* bp = (const bf16x8*)pk_dc + (size_t)(qq * KSTEP) * 64 + lane;
      #pragma unroll
      for (int s = 0; s < KSTEP; s++) {
        bf16x8 a = *(const bf16x8*)(arow + s * 32);
        acc = __builtin_amdgcn_mfma_f32_16x16x32_bf16(a, bp[(size_t)s * 64], acc, 0, 0, 0);
      }
      int co = qq * 16 + (lane & 15);
      int px = pxg * 16 + (lane >> 4) * 4;
      float bv = b_dc[co];
      size_t obase = ((size_t)b * HWv + (h0 + h2) * WWD + wb + px) * 64 + co;
      #pragma unroll
      for (int j = 0; j < 4; j++)
        ob[obase + (size_t)j * 64] =
            f2bf(acc[j] + bv + bf2f(x0bf[obase + (size_t)j * 64]));
    }
    if (h2 == 0) __syncthreads();                  // protect dsamp for row 1
  }
}

// ==== FUSED conv-w1+leaky + conv-w2+residual, 2-row x 32-col out ==========
__global__ __launch_bounds__(512) void rconv12_k(const u16* __restrict__ ob,
    const u16* __restrict__ pk_w1, const u16* __restrict__ pk_w2,
    const float* __restrict__ b1, const float* __restrict__ b2,
    float* __restrict__ outp) {
  #define R2COLS 36
  __shared__ __align__(16) u16 stage[6 * R2COLS * CSTR];  // 31,104 B
  __shared__ __align__(16) u16 zlds[144 * CSTR];          // 20,736 B
  u32* stage32 = (u32*)stage;
  int tid = threadIdx.x;
  int lane = tid & 63, q = tid >> 6;
  int blk = (blockIdx.x & 7) * 64 + (blockIdx.x >> 3);   // XCD swizzle (512)
  int wq = blk & 3, rp = (blk >> 2) & 63, b = blk >> 8;
  int h0 = rp * 2, wb = wq * 32;

  // ---- stage ob [6][36][64] bf16; 64 groups of 8 lanes, uint4
  {
    int lane4 = tid & 7, g8 = tid >> 3;
    const u32* inb = (const u32*)ob + (size_t)b * HWv * 32 + lane4 * 4;
    #pragma unroll
    for (int i = 0; i < 4; i++) {
      int u = g8 + 64 * i;
      if (u < 6 * R2COLS) {
        int r = u / R2COLS, c = u % R2COLS;
        int hh = h0 - 2 + r, ww = wb - 2 + c;
        uint4 v = {0u, 0u, 0u, 0u};
        if ((unsigned)hh < HH && (unsigned)ww < WWD)
          v = *(const uint4*)(inb + (size_t)(hh * WWD + ww) * 32);
        *(uint4*)(stage32 + u * (CSTR / 2) + lane4 * 4) = v;
      }
    }
  }
  __syncthreads();

  // ---- conv1: z1 = leaky(w1 * ob + b1) on the [4][34]=136 px halo grid
  // 18 tasks = 9 px-groups x 2 co-pairs; 8 waves, 3 passes; acc[2].
  // z1 halo pixels OUTSIDE the image are zeroed (conv2 zero padding).
  #pragma unroll
  for (int t = 0; t < 3; t++) {
    int task = q + 8 * t;
    if (task < 18) {
      int g = task >> 1, copair = task & 1;
      int p = g * 16 + (lane & 15);
      if (p > 135) p = 135;                       // pad px clamp (group 8)
      int r1 = p / 34, c1 = p % 34;
      f32x4 acc[2] = {{0,0,0,0},{0,0,0,0}};
      const bf16x8* bp = (const bf16x8*)pk_w1 + (size_t)(copair * 2 * KSTEP) * 64 + lane;
      #pragma unroll
      for (int s = 0; s < KSTEP; s++) {
        int kk = s >> 1;
        int addr = ((r1 + kk / 3) * R2COLS + c1 + kk % 3) * CSTR
                   + (s & 1) * 32 + (lane >> 4) * 8;
        bf16x8 a = *(const bf16x8*)(stage + addr);
        acc[0] = __builtin_amdgcn_mfma_f32_16x16x32_bf16(a, bp[(size_t)s * 64], acc[0], 0, 0, 0);
        acc[1] = __builtin_amdgcn_mfma_f32_16x16x32_bf16(a, bp[(size_t)(KSTEP + s) * 64], acc[1], 0, 0, 0);
      }
      int prow = g * 16 + (lane >> 4) * 4;
      #pragma unroll
      for (int tt = 0; tt < 2; tt++) {
        int co = copair * 32 + tt * 16 + (lane & 15);
        float bv = b1[co];
        #pragma unroll
        for (int j = 0; j < 4; j++) {
          int pp = prow + j;                      // may reach 143 (unused rows)
          int rr = pp / 34, cc = pp % 34;
          bool inimg = ((unsigned)(h0 - 1 + rr) < HH) && ((unsigned)(wb - 1 + cc) < WWD);
          float v = acc[tt][j] + bv;
          v = v >= 0.f ? v : 0.2f * v;
          zlds[pp * CSTR + co] = inimg ? f2bf(v) : (u16)0;
        }
      }
    }
  }
  __syncthreads();

  // ---- conv2: out = w2 * z1 + b2 + ob   (8 waves = r x cg x copair)
  int r = q & 1, cg = (q >> 1) & 1, copair = q >> 2;
  f32x4 acc2[2] = {{0,0,0,0},{0,0,0,0}};
  const bf16x8* bp2 = (const bf16x8*)pk_w2 + (size_t)(copair * 2 * KSTEP) * 64 + lane;
  #pragma unroll
  for (int s = 0; s < KSTEP; s++) {
    int kk = s >> 1;
    int p = (r + kk / 3) * 34 + cg * 16 + (lane & 15) + (kk % 3);
    int addr = p * CSTR + (s & 1) * 32 + (lane >> 4) * 8;
    bf16x8 a = *(const bf16x8*)(zlds + addr);
    acc2[0] = __builtin_amdgcn_mfma_f32_16x16x32_bf16(a, bp2[(size_t)s * 64], acc2[0], 0, 0, 0);
    acc2[1] = __builtin_amdgcn_mfma_f32_16x16x32_bf16(a, bp2[(size_t)(KSTEP + s) * 64], acc2[1], 0, 0, 0);
  }
  __syncthreads();                                 // zlds reads done -> reuse

  // ---- epilogue: +bias +residual(from stage), transpose to NCHW
  float* ot = (float*)zlds;                        // [64 co][72] f32 = 18,432 B
  int pxc = cg * 16 + (lane >> 4) * 4;             // col within 32
  #pragma unroll
  for (int t = 0; t < 2; t++) {
    int co = copair * 32 + t * 16 + (lane & 15);
    float bv = b2[co];
    #pragma unroll
    for (int j = 0; j < 4; j++) {
      int c = pxc + j;
      u16 resv = stage[((r + 2) * R2COLS + c + 2) * CSTR + co];
      ot[co * 72 + r * 36 + c] = acc2[t][j] + bv + bf2f(resv);
    }
  }
  __syncthreads();
  int co = tid >> 3, seg = tid & 7;                // 2 rows x 4 col-segments
  int r2 = seg >> 2, c8 = (seg & 3) * 8;
  const float4* src4 = (const float4*)(ot + co * 72 + r2 * 36 + c8);
  float4 v0 = src4[0], v1 = src4[1];
  float* dst = outp + ((size_t)b * CCH + co) * HWv + (h0 + r2) * WWD + wb + c8;
  *(float4*)dst = v0;
  *(float4*)(dst + 4) = v1;
}

extern "C" void kernel_launch(void* const* d_in, const int* in_sizes, int n_in,
                              void* d_out, int out_size, void* d_ws, size_t ws_size,
                              hipStream_t stream) {
  const float* x    = (const float*)d_in[0];
  const float* y    = (const float*)d_in[1];
  const float* w0   = (const float*)d_in[2];
  const float* b0   = (const float*)d_in[3];
  const float* w_om = (const float*)d_in[4];
  const float* b_om = (const float*)d_in[5];
  const float* w_dc = (const float*)d_in[6];
  const float* b_dc = (const float*)d_in[7];
  const float* w1   = (const float*)d_in[8];
  const float* b1   = (const float*)d_in[9];
  const float* w2   = (const float*)d_in[10];
  const float* b2   = (const float*)d_in[11];
  float* out = (float*)d_out;

  const size_t NFULL = (size_t)BB * CCH * HWv;   // 2,097,152
  const size_t NPACK = 4 * KSTEP * 64 * 8;       // 36,864 bf16
  u16* x0bf = (u16*)d_ws;                        // NFULL bf16
  u16* ob   = x0bf + NFULL;                      // NFULL bf16
  u16* yt   = ob + NFULL;                        // NFULL bf16
  u16* pk_dc = yt + NFULL;
  u16* pk_w1 = pk_dc + NPACK;
  u16* pk_w2 = pk_w1 + NPACK;
  u16* pk_om = pk_w2 + NPACK;

  const int NB = (int)((size_t)BB * HWv / 64);   // 512

  // 1. fused y-transpose + conv1x1 (+ weight packs in extra blocks)
  c1y_pack_k<<<NB + 576, 256, 0, stream>>>(x, y, w0, b0, w_dc, w1, w2, w_om,
                                           x0bf, yt, pk_dc, pk_w1, pk_w2, pk_om);
  // 2. fused om conv + deform conv + x0 residual -> ob (NHWC bf16)
  omd_k<<<NB, 512, 0, stream>>>(x0bf, yt, pk_om, pk_dc, b_om, b_dc, ob);
  // 3. fused conv w1 + leaky + conv w2 + residual -> out (NCHW f32)
  rconv12_k<<<NB, 512, 0, stream>>>(ob, pk_w1, pk_w2, b1, b2, out);
}

// Round 19
// 53.021 us; speedup vs baseline: 1.1023x; 1.1023x over previous
//
#include <hip/hip_runtime.h>
#include <hip/hip_bf16.h>
#include <math.h>

#define BB 2
#define CCH 64
#define HH 128
#define WWD 128
#define HWv (HH*WWD)
#define KK 9
#define KSTEP 18        // 576/32
#define OMKS 36         // 1152/32
// 2-row x 32-col tiles
#define TCOLS 34
#define CSTR 72         // padded 64-ch run stride (bf16): 64 + 8
#define CSTR2 136       // padded 128-ch run stride (bf16): 128 + 8
#define DROW 584        // deform samp row stride (bf16): 576 + 8

typedef __attribute__((ext_vector_type(8))) short bf16x8;
typedef __attribute__((ext_vector_type(4))) float f32x4;
typedef unsigned short u16;
typedef unsigned int u32;

__device__ inline u16 f2bf(float f) {
  __hip_bfloat16 h = __float2bfloat16(f);
  return *reinterpret_cast<u16*>(&h);
}
__device__ inline u32 f2bf2(float lo, float hi) {
  return ((u32)f2bf(hi) << 16) | (u32)f2bf(lo);
}
__device__ inline float bfLO(u32 v) { return __uint_as_float(v << 16); }
__device__ inline float bfHI(u32 v) { return __uint_as_float(v & 0xffff0000u); }
__device__ inline float bf2f(u16 v) { return __uint_as_float((u32)v << 16); }

// ==== kernel 1: blocks [0,512) = y-transpose + conv1x1 (w0 packed in-reg);
//                blocks [512,1088) = weight packs for dc/w1/w2/om ===========
__global__ __launch_bounds__(256) void c1y_pack_k(const float* __restrict__ x,
    const float* __restrict__ y, const float* __restrict__ w0,
    const float* __restrict__ b0, const float* __restrict__ w_dc,
    const float* __restrict__ w1, const float* __restrict__ w2,
    const float* __restrict__ w_om, u16* __restrict__ x0bf,
    u16* __restrict__ yt, u16* __restrict__ pk_dc, u16* __restrict__ pk_w1,
    u16* __restrict__ pk_w2, u16* __restrict__ pk_om) {
  #define S1ROW 72
  __shared__ __align__(16) float smem[64 * 65];    // 16,640 B; aliased below
  int tid = threadIdx.x;

  if (blockIdx.x >= 512) {                         // ---- pack path ----
    int blk = blockIdx.x - 512;                    // 0..575
    if (blk < 432) {
      const float* w = blk < 144 ? w_dc : (blk < 288 ? w1 : w2);
      u16* dst = blk < 144 ? pk_dc : (blk < 288 ? pk_w1 : pk_w2);
      int idx = (blk % 144) * 256 + tid;
      int j = idx & 7, l = (idx >> 3) & 63;
      int s = (idx >> 9) % 18, q = idx / 9216;
      int co = q * 16 + (l & 15);
      int kp = s * 32 + (l >> 4) * 8 + j;          // < 576
      dst[idx] = f2bf(w[(co * 64 + (kp & 63)) * 9 + (kp >> 6)]);
    } else {
      int idx = (blk - 432) * 256 + tid;
      int j = idx & 7, l = (idx >> 3) & 63;
      int s = (idx >> 9) % 36, q = idx / 18432;
      int co = q * 16 + (l & 15);
      int kp = s * 32 + (l >> 4) * 8 + j;          // < 1152
      pk_om[idx] = (co < 27)
          ? f2bf(w_om[(co * 128 + (kp & 127)) * 9 + (kp >> 7)]) : (u16)0;
    }
    return;
  }

  // ---- conv1x1y path ----
  u16* samp1 = (u16*)smem;                         // needs 9,216 B
  int lane = tid & 63, q = tid >> 6;
  int pixbase = blockIdx.x * 64;
  int hwb = pixbase & (HWv - 1);
  int b = pixbase >> 14;
  int co = q * 16 + (lane & 15);
  int g = lane >> 4;

  // w0 fragments in-register (L2-resident 16 KB table)
  bf16x8 wfrag[2];
  #pragma unroll
  for (int s = 0; s < 2; s++) {
    const float* wp = w0 + co * 64 + s * 32 + g * 8;
    u16 tw[8];
    #pragma unroll
    for (int j = 0; j < 8; j++) tw[j] = f2bf(wp[j]);
    wfrag[s] = *(bf16x8*)tw;
  }

  // ---- phase Y: transpose y for these 64 px ----
  {
    const float* src = y + (size_t)b * CCH * HWv;
    #pragma unroll
    for (int i = 0; i < 16; i++) {
      int ci = i * 4 + q;
      smem[ci * 65 + lane] = src[(size_t)ci * HWv + hwb + lane];
    }
    __syncthreads();
    u32* dst32 = (u32*)(yt + ((size_t)b * HWv + hwb) * 64);
    int lane2 = tid & 31, rr = tid >> 5;
    #pragma unroll
    for (int i = 0; i < 8; i++) {
      int row = i * 8 + rr;
      dst32[row * 32 + lane2] = f2bf2(smem[(2 * lane2) * 65 + row],
                                      smem[(2 * lane2 + 1) * 65 + row]);
    }
    __syncthreads();                               // smem dead -> reuse
  }

  // ---- phase X: conv1x1 ----
  {
    u16 tmp[16];
    #pragma unroll
    for (int i = 0; i < 16; i++) {
      int ci = q * 16 + i;
      tmp[i] = f2bf(x[((size_t)b * CCH + ci) * HWv + hwb + lane]);
    }
    #pragma unroll
    for (int i = 0; i < 2; i++)
      *(bf16x8*)(samp1 + lane * S1ROW + q * 16 + i * 8) = *(bf16x8*)(tmp + i * 8);
  }
  __syncthreads();
  f32x4 acc[4] = {{0,0,0,0},{0,0,0,0},{0,0,0,0},{0,0,0,0}};
  #pragma unroll
  for (int s = 0; s < 2; s++) {
    #pragma unroll
    for (int t = 0; t < 4; t++) {
      bf16x8 a = *(const bf16x8*)(samp1 + (t * 16 + (lane & 15)) * S1ROW + g * 8 + s * 32);
      acc[t] = __builtin_amdgcn_mfma_f32_16x16x32_bf16(a, wfrag[s], acc[t], 0, 0, 0);
    }
  }
  float bv = b0[co];
  u16* dst = x0bf + ((size_t)b * HWv + hwb + g * 4) * 64 + co;
  #pragma unroll
  for (int t = 0; t < 4; t++)
    #pragma unroll
    for (int r = 0; r < 4; r++)
      dst[(size_t)(t * 16 + r) * 64] = f2bf(acc[t][r] + bv);
}

// ==== FUSED om conv + deform conv, 2-row x 32-col tile, 512 thr ============
// XCD-swizzled blocks; single prm pass; compact prm (20 B) + bf16 omv
// => LDS 52,480 B => 3 blocks/CU.
__global__ __launch_bounds__(512) void omd_k(const u16* __restrict__ x0bf,
    const u16* __restrict__ yt, const u16* __restrict__ pk_om,
    const u16* __restrict__ pk_dc, const float* __restrict__ b_om,
    const float* __restrict__ b_dc, u16* __restrict__ ob) {
  __shared__ __align__(16) u16 A[18688];           // 37,376 B (stage / dsamp)
  __shared__ __align__(16) u32 prmS[576 * 5];      // 11,520 B (both rows)
  __shared__ __align__(16) u16 omv16[64 * 28];     //  3,584 B   (tot 52,480)
  u32* A32 = (u32*)A;
  u32* dsamp32 = (u32*)A;
  u16* dsamp = A;
  int tid = threadIdx.x;
  int lane = tid & 63, q = tid >> 6;
  int blk = (blockIdx.x & 7) * 64 + (blockIdx.x >> 3);   // XCD swizzle (512)
  int wq = blk & 3, rp = (blk >> 2) & 63, b = blk >> 8;
  int h0 = rp * 2, wb = wq * 32;
  const u32* x0b32 = (const u32*)x0bf + (size_t)b * HWv * 32;
  const u32* yt32  = (const u32*)yt + (size_t)b * HWv * 32;

  // ---- phase 1: stage [4][34][128ch]; 16 groups of 32 lanes, uint2
  {
    int lane2 = tid & 31, g16 = tid >> 5;
    int cofs = lane2 * 2;
    const u32* srcb = (lane2 < 16) ? (x0b32 + cofs) : (yt32 + cofs - 32);
    #pragma unroll
    for (int i = 0; i < 9; i++) {
      int u = g16 + 16 * i;
      if (u < 4 * TCOLS) {
        int r = u / TCOLS, c = u % TCOLS;
        int hh = h0 - 1 + r, ww = wb - 1 + c;
        uint2 v = {0u, 0u};
        if ((unsigned)hh < HH && (unsigned)ww < WWD)
          v = *(const uint2*)(srcb + (size_t)(hh * WWD + ww) * 32);
        *(uint2*)(A32 + u * (CSTR2 / 2) + cofs) = v;
      }
    }
  }
  __syncthreads();

  // ---- phase 2: om MFMA -> omv16 (bf16)
  {
    int r = q & 1, cg = (q >> 1) & 1, cohalf = q >> 2;
    f32x4 acc = {0.f, 0.f, 0.f, 0.f};
    const bf16x8* bp = (const bf16x8*)pk_om + (size_t)(cohalf * OMKS) * 64 + lane;
    #pragma unroll
    for (int s = 0; s < OMKS; s++) {
      int kk = s >> 2;
      int addr = ((r + kk / 3) * TCOLS + cg * 16 + (lane & 15) + (kk % 3)) * CSTR2
                 + (s & 3) * 32 + (lane >> 4) * 8;
      bf16x8 a = *(const bf16x8*)(A + addr);
      acc = __builtin_amdgcn_mfma_f32_16x16x32_bf16(a, bp[(size_t)s * 64], acc, 0, 0, 0);
    }
    int co = cohalf * 16 + (lane & 15);
    if (co < 27) {
      float bv = b_om[co];
      int px = r * 32 + cg * 16 + (lane >> 4) * 4;
      #pragma unroll
      for (int j = 0; j < 4; j++)
        omv16[(px + j) * 28 + co] = f2bf(acc[j] + bv);
    }
  }
  __syncthreads();

  // ---- phase 3a: prm for BOTH rows (576 entries over 512 threads)
  #pragma unroll
  for (int t = 0; t < 2; t++) {
    int u = tid + 512 * t;
    if (u < 576) {
      int pl = u / KK, k = u % KK;                 // pl 0..63
      int r2 = pl >> 5, cl = pl & 31;
      const u16* omp = omv16 + pl * 28;
      float dy = bf2f(omp[2 * k]), dx = bf2f(omp[2 * k + 1]);
      float mk = 2.f / (1.f + expf(-bf2f(omp[18 + k])));
      float ys = (float)(h0 + r2 - 1 + k / 3) + dy;
      float xs = (float)(wb + cl - 1 + k % 3) + dx;
      float y0f = floorf(ys), x0f = floorf(xs);
      float ty = ys - y0f, tx = xs - x0f;
      int yi = (int)y0f, xi = (int)x0f;
      bool y0v = (unsigned)yi < HH, y1v = (unsigned)(yi + 1) < HH;
      bool x0v = (unsigned)xi < WWD, x1v = (unsigned)(xi + 1) < WWD;
      float w00 = (1.f - ty) * (1.f - tx) * mk * ((y0v && x0v) ? 1.f : 0.f);
      float w01 = (1.f - ty) * tx * mk * ((y0v && x1v) ? 1.f : 0.f);
      float w10 = ty * (1.f - tx) * mk * ((y1v && x0v) ? 1.f : 0.f);
      float w11 = ty * tx * mk * ((y1v && x1v) ? 1.f : 0.f);
      u32 y0c = (u32)min(max(yi, 0), HH - 1);
      u32 y1c = (u32)min(max(yi + 1, 0), HH - 1);
      u32 x0c = (u32)min(max(xi, 0), WWD - 1);
      u32 x1c = (u32)min(max(xi + 1, 0), WWD - 1);
      u32* p = prmS + u * 5;
      p[0] = y0c | (y1c << 8) | (x0c << 16) | (x1c << 24);
      p[1] = __float_as_uint(w00);
      p[2] = __float_as_uint(w01);
      p[3] = __float_as_uint(w10);
      p[4] = __float_as_uint(w11);
    }
  }
  __syncthreads();

  // ---- phase 3b/3c: per row: gather (16-lane uint2 groups) -> MFMA -> ob
  #pragma unroll
  for (int h2 = 0; h2 < 2; h2++) {
    {
      int lane4 = tid & 15, g16 = tid >> 4;        // 32 groups
      const u32* ytb = yt32 + lane4 * 2;
      #pragma unroll
      for (int i = 0; i < 9; i++) {
        int u = g16 + 32 * i;                      // 0..287
        int k = u % 9, pix = u / 9;
        const u32* pp = prmS + (h2 * 288 + u) * 5;
        u32 pk = pp[0];
        float w00 = __uint_as_float(pp[1]), w01 = __uint_as_float(pp[2]);
        float w10 = __uint_as_float(pp[3]), w11 = __uint_as_float(pp[4]);
        int y0o = (int)(pk & 255u) << 12;          // *WWD*32
        int y1o = (int)((pk >> 8) & 255u) << 12;
        int x0o = (int)((pk >> 16) & 255u) << 5;   // *32
        int x1o = (int)(pk >> 24) << 5;
        uint2 v00 = *(const uint2*)(ytb + y0o + x0o);
        uint2 v01 = *(const uint2*)(ytb + y0o + x1o);
        uint2 v10 = *(const uint2*)(ytb + y1o + x0o);
        uint2 v11 = *(const uint2*)(ytb + y1o + x1o);
        float a0 = fmaf(bfLO(v00.x), w00, fmaf(bfLO(v01.x), w01,
                   fmaf(bfLO(v10.x), w10, bfLO(v11.x) * w11)));
        float a1 = fmaf(bfHI(v00.x), w00, fmaf(bfHI(v01.x), w01,
                   fmaf(bfHI(v10.x), w10, bfHI(v11.x) * w11)));
        float a2 = fmaf(bfLO(v00.y), w00, fmaf(bfLO(v01.y), w01,
                   fmaf(bfLO(v10.y), w10, bfLO(v11.y) * w11)));
        float a3 = fmaf(bfHI(v00.y), w00, fmaf(bfHI(v01.y), w01,
                   fmaf(bfHI(v10.y), w10, bfHI(v11.y) * w11)));
        uint2 o = {f2bf2(a0, a1), f2bf2(a2, a3)};
        *(uint2*)(dsamp32 + pix * (DROW / 2) + k * 32 + lane4 * 2) = o;
      }
    }
    __syncthreads();
    {
      int qq = q & 3, pxg = q >> 2;
      f32x4 acc = {0.f, 0.f, 0.f, 0.f};
      const u16* arow = dsamp + (pxg * 16 + (lane & 15)) * DROW + (lane >> 4) * 8;
      const bf16x8* bp = (const bf16x8*)pk_dc + (size_t)(qq * KSTEP) * 64 + lane;
      #pragma unroll
      for (int s = 0; s < KSTEP; s++) {
        bf16x8 a = *(const bf16x8*)(arow + s * 32);
        acc = __builtin_amdgcn_mfma_f32_16x16x32_bf16(a, bp[(size_t)s * 64], acc, 0, 0, 0);
      }
      int co = qq * 16 + (lane & 15);
      int px = pxg * 16 + (lane >> 4) * 4;
      float bv = b_dc[co];
      size_t obase = ((size_t)b * HWv + (h0 + h2) * WWD + wb + px) * 64 + co;
      #pragma unroll
      for (int j = 0; j < 4; j++)
        ob[obase + (size_t)j * 64] =
            f2bf(acc[j] + bv + bf2f(x0bf[obase + (size_t)j * 64]));
    }
    if (h2 == 0) __syncthreads();                  // protect dsamp for row 1
  }
}

// ==== FUSED conv-w1+leaky + conv-w2+residual, 2-row x 32-col out ==========
__global__ __launch_bounds__(512) void rconv12_k(const u16* __restrict__ ob,
    const u16* __restrict__ pk_w1, const u16* __restrict__ pk_w2,
    const float* __restrict__ b1, const float* __restrict__ b2,
    float* __restrict__ outp) {
  #define R2COLS 36
  __shared__ __align__(16) u16 stage[6 * R2COLS * CSTR];  // 31,104 B
  __shared__ __align__(16) u16 zlds[144 * CSTR];          // 20,736 B
  u32* stage32 = (u32*)stage;
  int tid = threadIdx.x;
  int lane = tid & 63, q = tid >> 6;
  int blk = (blockIdx.x & 7) * 64 + (blockIdx.x >> 3);   // XCD swizzle (512)
  int wq = blk & 3, rp = (blk >> 2) & 63, b = blk >> 8;
  int h0 = rp * 2, wb = wq * 32;

  // ---- stage ob [6][36][64] bf16, uint2 copy (216 units, 32 groups)
  {
    int lane4 = tid & 15, g16 = tid >> 4;
    const u32* inb = (const u32*)ob + (size_t)b * HWv * 32 + lane4 * 2;
    #pragma unroll
    for (int i = 0; i < 7; i++) {
      int u = g16 + 32 * i;
      if (u < 6 * R2COLS) {
        int r = u / R2COLS, c = u % R2COLS;
        int hh = h0 - 2 + r, ww = wb - 2 + c;
        uint2 v = {0u, 0u};
        if ((unsigned)hh < HH && (unsigned)ww < WWD)
          v = *(const uint2*)(inb + (size_t)(hh * WWD + ww) * 32);
        *(uint2*)(stage32 + u * (CSTR / 2) + lane4 * 2) = v;
      }
    }
  }
  __syncthreads();

  // ---- conv1: z1 = leaky(w1 * ob + b1) on the [4][34]=136 px halo grid
  // 36 tasks = 9 px-groups x 4 co-quadrants; 8 waves round-robin.
  // z1 halo pixels OUTSIDE the image are zeroed (conv2 zero padding).
  #pragma unroll
  for (int t = 0; t < 5; t++) {
    int task = q + 8 * t;
    if (task < 36) {
      int g = task >> 2, coq = task & 3;
      int p = g * 16 + (lane & 15);
      if (p > 135) p = 135;                       // pad px clamp (group 8)
      int r1 = p / 34, c1 = p % 34;
      f32x4 acc = {0.f, 0.f, 0.f, 0.f};
      const bf16x8* bp = (const bf16x8*)pk_w1 + (size_t)(coq * KSTEP) * 64 + lane;
      #pragma unroll
      for (int s = 0; s < KSTEP; s++) {
        int kk = s >> 1;
        int addr = ((r1 + kk / 3) * R2COLS + c1 + kk % 3) * CSTR
                   + (s & 1) * 32 + (lane >> 4) * 8;
        bf16x8 a = *(const bf16x8*)(stage + addr);
        acc = __builtin_amdgcn_mfma_f32_16x16x32_bf16(a, bp[(size_t)s * 64], acc, 0, 0, 0);
      }
      int co = coq * 16 + (lane & 15);
      float bv = b1[co];
      int prow = g * 16 + (lane >> 4) * 4;
      #pragma unroll
      for (int j = 0; j < 4; j++) {
        int pp = prow + j;                        // may reach 143 (unused rows)
        int rr = pp / 34, cc = pp % 34;
        bool inimg = ((unsigned)(h0 - 1 + rr) < HH) && ((unsigned)(wb - 1 + cc) < WWD);
        float v = acc[j] + bv;
        v = v >= 0.f ? v : 0.2f * v;
        zlds[pp * CSTR + co] = inimg ? f2bf(v) : (u16)0;
      }
    }
  }
  __syncthreads();

  // ---- conv2: out = w2 * z1 + b2 + ob   (8 waves = r x cg x copair)
  int r = q & 1, cg = (q >> 1) & 1, copair = q >> 2;
  f32x4 acc2[2] = {{0,0,0,0},{0,0,0,0}};
  const bf16x8* bp2 = (const bf16x8*)pk_w2 + (size_t)(copair * 2 * KSTEP) * 64 + lane;
  #pragma unroll
  for (int s = 0; s < KSTEP; s++) {
    int kk = s >> 1;
    int p = (r + kk / 3) * 34 + cg * 16 + (lane & 15) + (kk % 3);
    int addr = p * CSTR + (s & 1) * 32 + (lane >> 4) * 8;
    bf16x8 a = *(const bf16x8*)(zlds + addr);
    acc2[0] = __builtin_amdgcn_mfma_f32_16x16x32_bf16(a, bp2[(size_t)s * 64], acc2[0], 0, 0, 0);
    acc2[1] = __builtin_amdgcn_mfma_f32_16x16x32_bf16(a, bp2[(size_t)(KSTEP + s) * 64], acc2[1], 0, 0, 0);
  }
  __syncthreads();                                 // zlds reads done -> reuse

  // ---- epilogue: +bias +residual(from stage), transpose to NCHW
  float* ot = (float*)zlds;                        // [64 co][72] f32 = 18,432 B
  int pxc = cg * 16 + (lane >> 4) * 4;             // col within 32
  #pragma unroll
  for (int t = 0; t < 2; t++) {
    int co = copair * 32 + t * 16 + (lane & 15);
    float bv = b2[co];
    #pragma unroll
    for (int j = 0; j < 4; j++) {
      int c = pxc + j;
      u16 resv = stage[((r + 2) * R2COLS + c + 2) * CSTR + co];
      ot[co * 72 + r * 36 + c] = acc2[t][j] + bv + bf2f(resv);
    }
  }
  __syncthreads();
  int co = tid >> 3, seg = tid & 7;                // 2 rows x 4 col-segments
  int r2 = seg >> 2, c8 = (seg & 3) * 8;
  const float4* src4 = (const float4*)(ot + co * 72 + r2 * 36 + c8);
  float4 v0 = src4[0], v1 = src4[1];
  float* dst = outp + ((size_t)b * CCH + co) * HWv + (h0 + r2) * WWD + wb + c8;
  *(float4*)dst = v0;
  *(float4*)(dst + 4) = v1;
}

extern "C" void kernel_launch(void* const* d_in, const int* in_sizes, int n_in,
                              void* d_out, int out_size, void* d_ws, size_t ws_size,
                              hipStream_t stream) {
  const float* x    = (const float*)d_in[0];
  const float* y    = (const float*)d_in[1];
  const float* w0   = (const float*)d_in[2];
  const float* b0   = (const float*)d_in[3];
  const float* w_om = (const float*)d_in[4];
  const float* b_om = (const float*)d_in[5];
  const float* w_dc = (const float*)d_in[6];
  const float* b_dc = (const float*)d_in[7];
  const float* w1   = (const float*)d_in[8];
  const float* b1   = (const float*)d_in[9];
  const float* w2   = (const float*)d_in[10];
  const float* b2   = (const float*)d_in[11];
  float* out = (float*)d_out;

  const size_t NFULL = (size_t)BB * CCH * HWv;   // 2,097,152
  const size_t NPACK = 4 * KSTEP * 64 * 8;       // 36,864 bf16
  u16* x0bf = (u16*)d_ws;                        // NFULL bf16
  u16* ob   = x0bf + NFULL;                      // NFULL bf16
  u16* yt   = ob + NFULL;                        // NFULL bf16
  u16* pk_dc = yt + NFULL;
  u16* pk_w1 = pk_dc + NPACK;
  u16* pk_w2 = pk_w1 + NPACK;
  u16* pk_om = pk_w2 + NPACK;

  const int NB = (int)((size_t)BB * HWv / 64);   // 512

  // 1. fused y-transpose + conv1x1 (+ weight packs in extra blocks)
  c1y_pack_k<<<NB + 576, 256, 0, stream>>>(x, y, w0, b0, w_dc, w1, w2, w_om,
                                           x0bf, yt, pk_dc, pk_w1, pk_w2, pk_om);
  // 2. fused om conv + deform conv + x0 residual -> ob (NHWC bf16)
  omd_k<<<NB, 512, 0, stream>>>(x0bf, yt, pk_om, pk_dc, b_om, b_dc, ob);
  // 3. fused conv w1 + leaky + conv w2 + residual -> out (NCHW f32)
  rconv12_k<<<NB, 512, 0, stream>>>(ob, pk_w1, pk_w2, b1, b2, out);
}